// Round 1
// baseline (295.813 us; speedup 1.0000x reference)
//
#include <hip/hip_runtime.h>

typedef _Float16 h8 __attribute__((ext_vector_type(8)));
typedef _Float16 h4 __attribute__((ext_vector_type(4)));
typedef float f32x4 __attribute__((ext_vector_type(4)));
typedef float f32x16 __attribute__((ext_vector_type(16)));

union HU { _Float16 h; unsigned short u; };
__device__ __forceinline__ unsigned short f2h(float f) { HU x; x.h = (_Float16)f; return x.u; }
__device__ __forceinline__ float h2f(unsigned short u) { HU x; x.u = u; return (float)x.h; }

#define MFMA16(a, b, c) __builtin_amdgcn_mfma_f32_16x16x32_f16((a), (b), (c), 0, 0, 0)
#define MFMA32(a, b, c) __builtin_amdgcn_mfma_f32_32x32x16_f16((a), (b), (c), 0, 0, 0)

// ---------------------------------------------------------------------------
// k_prep: identical to round 11 EXCEPT w2f is repacked for 32x32x16 MFMA:
//   per tap t (0..8): 64 lanes x h8, n = lane&31 (oc), k = (lane>>5)*8+j (ic).
// ---------------------------------------------------------------------------
__global__ void k_prep(const float* __restrict__ w1, const float* __restrict__ w2,
                       const float* __restrict__ w3,
                       const float* __restrict__ ptw1, const float* __restrict__ cfw1,
                       const float* __restrict__ ptw2, const float* __restrict__ ptw3,
                       const float* __restrict__ cfw2,
                       unsigned short* __restrict__ w1f,
                       unsigned short* __restrict__ w2f,
                       unsigned short* __restrict__ w3f,
                       unsigned short* __restrict__ w1hd,
                       unsigned short* __restrict__ w2hd,
                       unsigned short* __restrict__ w3hd) {
    int gid = blockIdx.x * 256 + threadIdx.x;
    int gs = gridDim.x * 256;
    for (int e = gid; e < 1024; e += gs) {
        int f = e >> 9, lane = (e >> 3) & 63, j = e & 7;
        int k = ((lane >> 4) << 3) + j, oc = lane & 15;
        int r, within;
        if (f == 0) { r = k >> 4; within = k & 15; }
        else        { r = 2;      within = k; }
        int tx = within >> 2, ch = within & 3;
        float v = 0.f;
        if (tx < 3 && ch < 3) v = w1[oc * 27 + ch * 9 + r * 3 + tx];
        w1f[e] = f2h(v);
    }
    // conv2 weights for 32x32x16: e = t*512 + lane*8 + j
    for (int e = gid; e < 4608; e += gs) {
        int j = e & 7, lane = (e >> 3) & 63, t = e >> 9;
        int oc = lane & 31, k = ((lane >> 5) << 3) + j;   // k = ic 0..15
        w2f[e] = f2h(w2[oc * 144 + k * 9 + t]);
    }
    for (int e = gid; e < 18432; e += gs) {
        int j = e & 7, lane = (e >> 3) & 63, fo = e >> 9;   // fo = (otp*9+t)*2+oti
        int oti = fo & 1, t = (fo >> 1) % 9, otp = (fo >> 1) / 9;
        int ic = ((lane >> 4) * 8) + j, oc = (otp * 2 + oti) * 16 + (lane & 15);
        w3f[e] = f2h(w3[oc * 288 + ic * 9 + t]);
    }
    for (int s = gid; s < 608 * 192; s += gs) {
        int k = s / 192, n = s - k * 192;
        float v = 0.f;
        if (k < 584) {
            int f = (k < 576) ? ((k & 63) * 9 + (k >> 6)) : k;
            v = (n < 128) ? ptw1[f * 128 + n] : cfw1[f * 64 + (n - 128)];
        }
        int kk = k >> 5, hi = (k & 31) >> 3, j = k & 7, nt = n >> 4;
        int e = (((kk * 12 + nt) << 6) | (hi << 4) | (n & 15)) << 3 | j;
        w1hd[e] = f2h(v);
    }
    for (int s = gid; s < 8192; s += gs) {
        int k = s >> 6, n = s & 63;
        float v = ptw2[k * 64 + n];
        int kk = k >> 5, hi = (k & 31) >> 3, j = k & 7, nt = n >> 4;
        int e = ((((kk << 2) | nt) << 6) | (hi << 4) | (n & 15)) << 3 | j;
        w2hd[e] = f2h(v);
    }
    for (int e = gid; e < 2048; e += gs) {
        int j = e & 7, lane = (e >> 3) & 63, kk = e >> 9;
        int k = kk * 32 + ((lane >> 4) * 8) + j, n = lane & 15;
        float v = 0.f;
        if (k < 64) { if (n < 2) v = ptw3[k * 2 + n]; }
        else        { if (n == 2) v = cfw2[k - 64]; }
        w3hd[e] = f2h(v);
    }
}

// ---------------------------------------------------------------------------
// k_fused, round 12: 512 threads (8 waves) per 32-sample block -> 6 waves/SIMD
// at the same 52.7 KB LDS (3 blocks/CU). conv2 rewritten on 32x32x16 MFMA
// (M=32 samples, K=16 ics exact, N=32 ocs exact): 1024 -> 256 MFMAs.
// ---------------------------------------------------------------------------
#define BDS4 260
#define BDH4 (16 * BDS4)
#define A1S 584
#define A2S 296
#define FTS 616
#define HSH 200
#define RA_OFF 19712
#define O_OFF 26112
#define LDSTOT 26368

__device__ __forceinline__ f32x16 conv2_pool(const unsigned short* __restrict__ Ab,
                                             const h8 (&W2r)[9], int kh, float b2v,
                                             int pr, int pc) {
    f32x16 pool;
    #pragma unroll
    for (int r = 0; r < 16; r++) pool[r] = 0.f;
    #pragma unroll
    for (int sy = 0; sy < 2; sy++)
        #pragma unroll
        for (int sx = 0; sx < 2; sx++) {
            const int oy = pr * 2 + sy, ox = pc * 2 + sx;
            f32x16 acc;
            #pragma unroll
            for (int r = 0; r < 16; r++) acc[r] = 0.f;
            #pragma unroll
            for (int dy = -1; dy <= 1; dy++) {
                const int ry = oy + dy;
                if (ry < 0 || ry > 5) continue;
                #pragma unroll
                for (int dx = -1; dx <= 1; dx++) {
                    const int rx = ox + dx;
                    if (rx < 0 || rx > 5) continue;
                    h8 a = *(const h8*)&Ab[(ry * 6 + rx) * 16 + kh * 8];
                    acc = MFMA32(a, W2r[(dy + 1) * 3 + (dx + 1)], acc);
                }
            }
            #pragma unroll
            for (int r = 0; r < 16; r++)
                pool[r] = fmaxf(pool[r], acc[r] + b2v);  // relu fused via 0-init
        }
    return pool;
}

__global__ __launch_bounds__(512, 6) void k_fused(
    const float* __restrict__ board,
    const float* __restrict__ b1, const float* __restrict__ b2,
    const float* __restrict__ b3, const float* __restrict__ qp,
    const unsigned short* __restrict__ w1f,
    const unsigned short* __restrict__ w2f,
    const unsigned short* __restrict__ w3f,
    const unsigned short* __restrict__ w1hd,
    const unsigned short* __restrict__ w2hd,
    const unsigned short* __restrict__ w3hd,
    const float* __restrict__ ptb1, const float* __restrict__ ptb2,
    const float* __restrict__ ptb3, const float* __restrict__ cfb1,
    const float* __restrict__ cfb2,
    float* __restrict__ out)
{
    __shared__ __align__(16) unsigned short LDSH[LDSTOT];
    const int tid = threadIdx.x, wid = tid >> 6, lane = tid & 63;
    const int col = lane & 15, q = lane >> 4;
    const long long gg0 = (long long)blockIdx.x * 32;
    const f32x4 ZERO4 = {0.f, 0.f, 0.f, 0.f};

    unsigned short* Hb = LDSH + RA_OFF;               // overlays BD (dead)
    float* O = (float*)(LDSH + O_OFF);

    // ---- 1. zero BD staging buffer ----
    for (int e = tid; e < BDH4 / 4; e += 512)
        ((unsigned long long*)(LDSH + RA_OFF))[e] = 0ULL;
    __syncthreads();

    // ---- 2. per-group: stage board (ch-pad-4) -> quantum + conv1 ----
    float qv[2];
    h8 w1r0 = ((const h8*)w1f)[lane];
    h8 w1r1 = ((const h8*)w1f)[64 + lane];
    float b1v = b1[col];
    #pragma unroll
    for (int gi = 0; gi < 2; gi++) {
        for (int e = tid; e < 16 * 108; e += 512) {
            int r2 = e % 108, ch = r2 / 36, p = r2 % 36;
            int ss = e / 108;
            float v = board[(gg0 + gi * 16) * 108 + e];
            LDSH[RA_OFF + ss * BDS4 + ((p / 6 + 1) * 8 + (p % 6) + 1) * 4 + ch] =
                f2h(v);
        }
        __syncthreads();
        if (tid < 128) {
            int ss = tid >> 3, qq = tid & 7;
            int base = RA_OFF + ss * BDS4;
            int p8a = ((qq / 6 + 1) * 8 + (qq % 6) + 1) * 4;
            int e2 = (qq + 1) & 7;
            int p8b = ((e2 / 6 + 1) * 8 + (e2 % 6) + 1) * 4;
            float xq = h2f(LDSH[base + p8a]);
            float xn = h2f(LDSH[base + p8b]);
            float st = 0.f;
            for (int l = 0; l < 3; l++) {
                float a0 = qp[l * 24 + qq * 3], a1 = qp[l * 24 + qq * 3 + 1],
                      a2 = qp[l * 24 + qq * 3 + 2];
                st = sinf(a0 * xq) * cosf(a1 * xn) + tanhf(a2 * st);
            }
            qv[gi] = st;
        }
        {
            unsigned short* A1g = LDSH + gi * 9856;
            const int bs = RA_OFF + col * BDS4;
            const int rsel = q >> 1, wo = (q & 1) * 8;
            // 36 positions over 8 waves: waves 0-3 take 5, waves 4-7 take 4
            const int p0 = wid * 4 + (wid < 4 ? wid : 4);
            const int pe = p0 + (wid < 4 ? 5 : 4);
            for (int p = p0; p < pe; p++) {
                int y = p / 6, x = p % 6;
                int ab1 = bs + ((y + rsel) * 8 + x) * 4 + wo;
                int ab2 = bs + ((y + 2) * 8 + x) * 4 + wo;
                union { h8 v; h4 h[2]; } a1v, a2v;
                a1v.h[0] = *(const h4*)&LDSH[ab1];
                a1v.h[1] = *(const h4*)&LDSH[ab1 + 4];
                a2v.h[0] = *(const h4*)&LDSH[ab2];
                a2v.h[1] = *(const h4*)&LDSH[ab2 + 4];
                f32x4 c = MFMA16(a1v.v, w1r0, ZERO4);
                c = MFMA16(a2v.v, w1r1, c);
                #pragma unroll
                for (int r = 0; r < 4; r++)
                    A1g[(q * 4 + r) * A1S + p * 16 + col] =
                        f2h(fmaxf(c[r] + b1v, 0.f));
            }
        }
        __syncthreads();
    }

    // ---- 3. conv2 (32x32x16): wave wid owns pooled pos wid; wave 0 also pos 8
    {
        h8 W2r[9];
        #pragma unroll
        for (int t = 0; t < 9; t++)
            W2r[t] = ((const h8*)w2f)[t * 64 + lane];
        const int m32 = lane & 31, kh = lane >> 5;
        const float b2v = b2[m32];                  // oc = lane&31 in D
        const unsigned short* Ab = LDSH + (m32 >> 4) * 9856 + (m32 & 15) * A1S;

        if (wid == 0) {
            // 9th pooled pos: stash in scratch (BD region, dead) pre-barrier
            f32x16 p8 = conv2_pool(Ab, W2r, kh, b2v, 2, 2);
            #pragma unroll
            for (int r = 0; r < 16; r++) {
                int s = (r & 3) + 8 * (r >> 2) + 4 * kh;
                LDSH[RA_OFF + s * 32 + m32] = f2h(p8[r]);
            }
        }
        f32x16 pool = conv2_pool(Ab, W2r, kh, b2v, wid / 3, wid % 3);
        __syncthreads();   // all A1 reads (+ scratch write) done before A2 overlays
        #pragma unroll
        for (int r = 0; r < 16; r++) {
            int s = (r & 3) + 8 * (r >> 2) + 4 * kh;
            LDSH[(s >> 4) * 9856 + (s & 15) * A2S + wid * 32 + m32] = f2h(pool[r]);
        }
        for (int e = tid; e < 1024; e += 512) {     // copy scratch -> A2 pos 8
            int s = e >> 5;
            LDSH[(s >> 4) * 9856 + (s & 15) * A2S + 8 * 32 + (e & 31)] =
                LDSH[RA_OFF + e];
        }
    }
    __syncthreads();

    // ---- 4. conv3 -> registers: wave = (group, 16-oc tile) ----
    f32x4 c3[9];
    {
        const int g3 = wid >> 2, ot = wid & 3;
        const unsigned short* A2g = LDSH + g3 * 9856;
        h8 W3r[9];
        #pragma unroll
        for (int t = 0; t < 9; t++)
            W3r[t] = ((const h8*)w3f)[((ot >> 1) * 18 + t * 2 + (ot & 1)) * 64 + lane];
        const int sA2 = col * A2S;
        #pragma unroll
        for (int p = 0; p < 9; p++) {
            const int y = p / 3, x = p % 3;
            f32x4 acc = ZERO4;
            #pragma unroll
            for (int t = 0; t < 9; t++) {
                const int sy = y + t / 3 - 1, sx = x + t % 3 - 1;
                if (sy < 0 || sy >= 3 || sx < 0 || sx >= 3) continue;
                h8 a = *(const h8*)&A2g[sA2 + (sy * 3 + sx) * 32 + q * 8];
                acc = MFMA16(a, W3r[t], acc);
            }
            c3[p] = acc;
        }
    }
    __syncthreads();   // all A2 reads done before FT overlays region

    // ---- 5. write FT [p][oc] + quantum + zero tail cols 584..615 ----
    {
        const int g3 = wid >> 2, ot = wid & 3;
        float b3v = b3[ot * 16 + col];
        #pragma unroll
        for (int p = 0; p < 9; p++)
            #pragma unroll
            for (int r = 0; r < 4; r++) {
                int row = g3 * 16 + q * 4 + r;
                LDSH[row * FTS + p * 64 + ot * 16 + col] =
                    f2h(fmaxf(c3[p][r] + b3v, 0.f));
            }
        if (tid < 128) {
            int ss = tid >> 3, qq = tid & 7;
            LDSH[ss * FTS + 576 + qq] = f2h(qv[0]);
            LDSH[(ss + 16) * FTS + 576 + qq] = f2h(qv[1]);
        }
        for (int e = tid; e < 1024; e += 512)
            LDSH[(e >> 5) * FTS + 584 + (e & 31)] = 0;
    }
    __syncthreads();

    // ---- 6. heads L1: K=608 (19 kk); wave = (mt, 3 nt-tiles) of 24 tiles ----
    {
        f32x4 acc[3];
        acc[0] = ZERO4; acc[1] = ZERO4; acc[2] = ZERO4;
        const h8* wp1 = (const h8*)w1hd;
        const int mt = wid & 1, ntb = (wid >> 1) * 3;
        for (int kk = 0; kk < 19; kk++) {
            h8 a = *(const h8*)&LDSH[(mt * 16 + col) * FTS + kk * 32 + q * 8];
            #pragma unroll
            for (int nt = 0; nt < 3; nt++) {
                h8 b = wp1[(kk * 12 + ntb + nt) * 64 + lane];
                acc[nt] = MFMA16(a, b, acc[nt]);
            }
        }
        #pragma unroll
        for (int nt = 0; nt < 3; nt++) {
            int ntg = ntb + nt;
            float bv = (ntg < 8) ? ptb1[ntg * 16 + col] : cfb1[(ntg - 8) * 16 + col];
            #pragma unroll
            for (int r = 0; r < 4; r++)
                Hb[(mt * 16 + q * 4 + r) * HSH + ntg * 16 + col] =
                    f2h(fmaxf(acc[nt][r] + bv, 0.f));
        }
    }
    __syncthreads();

    // ---- 7. heads L2: wave = (mt, nt) of 8 tiles ----
    {
        f32x4 acc2 = ZERO4;
        const h8* wp2 = (const h8*)w2hd;
        const int mt = wid & 1, nt2 = wid >> 1;
        #pragma unroll
        for (int kk = 0; kk < 4; kk++) {
            h8 a = *(const h8*)&Hb[(mt * 16 + col) * HSH + kk * 32 + q * 8];
            h8 b = wp2[(kk * 4 + nt2) * 64 + lane];
            acc2 = MFMA16(a, b, acc2);
        }
        __syncthreads();   // all L2 reads done before overwriting cols 0..63
        float bv2 = ptb2[nt2 * 16 + col];
        #pragma unroll
        for (int r = 0; r < 4; r++)
            Hb[(mt * 16 + q * 4 + r) * HSH + nt2 * 16 + col] =
                f2h(fmaxf(acc2[r] + bv2, 0.f));
    }
    __syncthreads();

    // ---- 8. heads L3 + epilogue: waves 0,1 handle mt = wid ----
    if (wid < 2) {
        const int mt = wid;
        f32x4 a3 = ZERO4;
        #pragma unroll
        for (int kk = 0; kk < 4; kk++) {
            int base = (kk < 2) ? kk * 32 : kk * 32 + 64;
            h8 a = *(const h8*)&Hb[(mt * 16 + col) * HSH + base + q * 8];
            h8 b = ((const h8*)w3hd)[kk * 64 + lane];
            a3 = MFMA16(a, b, a3);
        }
        if (col < 3) {
            float bv = (col < 2) ? ptb3[col] : cfb2[0];
            #pragma unroll
            for (int r = 0; r < 4; r++)
                O[(mt * 16 + q * 4 + r) * 4 + col] = a3[r] + bv;
        }
        if (lane < 16) {
            int s = mt * 16 + lane;
            float l0 = O[s * 4 + 0], l1 = O[s * 4 + 1], l2 = O[s * 4 + 2];
            float m = fmaxf(l0, l1);
            float e0 = expf(l0 - m), e1 = expf(l1 - m);
            float inv = 1.f / (e0 + e1);
            float* op = out + (gg0 + s) * 3;
            op[0] = e0 * inv;
            op[1] = e1 * inv;
            op[2] = 1.f / (1.f + expf(-l2));
        }
    }
}

extern "C" void kernel_launch(void* const* d_in, const int* in_sizes, int n_in,
                              void* d_out, int out_size, void* d_ws, size_t ws_size,
                              hipStream_t stream) {
    const float* board = (const float*)d_in[0];
    const float* c1w  = (const float*)d_in[2];
    const float* c1b  = (const float*)d_in[3];
    const float* c2w  = (const float*)d_in[4];
    const float* c2b  = (const float*)d_in[5];
    const float* c3w  = (const float*)d_in[6];
    const float* c3b  = (const float*)d_in[7];
    const float* qp   = (const float*)d_in[8];
    const float* ptw1 = (const float*)d_in[9];
    const float* ptb1 = (const float*)d_in[10];
    const float* ptw2 = (const float*)d_in[11];
    const float* ptb2 = (const float*)d_in[12];
    const float* ptw3 = (const float*)d_in[13];
    const float* ptb3 = (const float*)d_in[14];
    const float* cfw1 = (const float*)d_in[15];
    const float* cfb1 = (const float*)d_in[16];
    const float* cfw2 = (const float*)d_in[17];
    const float* cfb2 = (const float*)d_in[18];
    float* out = (float*)d_out;

    int Btot = in_sizes[0] / 108;          // 65536

    unsigned short* w1f   = (unsigned short*)d_ws;
    unsigned short* w2f   = (unsigned short*)((char*)d_ws + 2048);
    unsigned short* w3f   = (unsigned short*)((char*)d_ws + 20480);
    unsigned short* w1hd  = (unsigned short*)((char*)d_ws + 57344);
    unsigned short* w2hd  = (unsigned short*)((char*)d_ws + 290816);
    unsigned short* w3hd  = (unsigned short*)((char*)d_ws + 307200);

    hipLaunchKernelGGL(k_prep, dim3(256), dim3(256), 0, stream,
                       c1w, c2w, c3w, ptw1, cfw1, ptw2, ptw3, cfw2,
                       w1f, w2f, w3f, w1hd, w2hd, w3hd);
    hipLaunchKernelGGL(k_fused, dim3(Btot / 32), dim3(512), 0, stream,
                       board, c1b, c2b, c3b, qp, w1f, w2f, w3f,
                       w1hd, w2hd, w3hd, ptb1, ptb2, ptb3, cfb1, cfb2, out);
}

// Round 2
// 185.166 us; speedup vs baseline: 1.5976x; 1.5976x over previous
//
#include <hip/hip_runtime.h>

typedef _Float16 h8 __attribute__((ext_vector_type(8)));
typedef _Float16 h4 __attribute__((ext_vector_type(4)));
typedef float f32x4 __attribute__((ext_vector_type(4)));
typedef float f32x16 __attribute__((ext_vector_type(16)));

union HU { _Float16 h; unsigned short u; };
__device__ __forceinline__ unsigned short f2h(float f) { HU x; x.h = (_Float16)f; return x.u; }
__device__ __forceinline__ float h2f(unsigned short u) { HU x; x.u = u; return (float)x.h; }

#define MFMA16(a, b, c) __builtin_amdgcn_mfma_f32_16x16x32_f16((a), (b), (c), 0, 0, 0)
#define MFMA32(a, b, c) __builtin_amdgcn_mfma_f32_32x32x16_f16((a), (b), (c), 0, 0, 0)

// ---------------------------------------------------------------------------
// k_prep: identical to round 12 (w2f packed for 32x32x16 MFMA:
//   per tap t (0..8): 64 lanes x h8, n = lane&31 (oc), k = (lane>>5)*8+j (ic)).
// ---------------------------------------------------------------------------
__global__ void k_prep(const float* __restrict__ w1, const float* __restrict__ w2,
                       const float* __restrict__ w3,
                       const float* __restrict__ ptw1, const float* __restrict__ cfw1,
                       const float* __restrict__ ptw2, const float* __restrict__ ptw3,
                       const float* __restrict__ cfw2,
                       unsigned short* __restrict__ w1f,
                       unsigned short* __restrict__ w2f,
                       unsigned short* __restrict__ w3f,
                       unsigned short* __restrict__ w1hd,
                       unsigned short* __restrict__ w2hd,
                       unsigned short* __restrict__ w3hd) {
    int gid = blockIdx.x * 256 + threadIdx.x;
    int gs = gridDim.x * 256;
    for (int e = gid; e < 1024; e += gs) {
        int f = e >> 9, lane = (e >> 3) & 63, j = e & 7;
        int k = ((lane >> 4) << 3) + j, oc = lane & 15;
        int r, within;
        if (f == 0) { r = k >> 4; within = k & 15; }
        else        { r = 2;      within = k; }
        int tx = within >> 2, ch = within & 3;
        float v = 0.f;
        if (tx < 3 && ch < 3) v = w1[oc * 27 + ch * 9 + r * 3 + tx];
        w1f[e] = f2h(v);
    }
    // conv2 weights for 32x32x16: e = t*512 + lane*8 + j
    for (int e = gid; e < 4608; e += gs) {
        int j = e & 7, lane = (e >> 3) & 63, t = e >> 9;
        int oc = lane & 31, k = ((lane >> 5) << 3) + j;   // k = ic 0..15
        w2f[e] = f2h(w2[oc * 144 + k * 9 + t]);
    }
    for (int e = gid; e < 18432; e += gs) {
        int j = e & 7, lane = (e >> 3) & 63, fo = e >> 9;   // fo = (otp*9+t)*2+oti
        int oti = fo & 1, t = (fo >> 1) % 9, otp = (fo >> 1) / 9;
        int ic = ((lane >> 4) * 8) + j, oc = (otp * 2 + oti) * 16 + (lane & 15);
        w3f[e] = f2h(w3[oc * 288 + ic * 9 + t]);
    }
    for (int s = gid; s < 608 * 192; s += gs) {
        int k = s / 192, n = s - k * 192;
        float v = 0.f;
        if (k < 584) {
            int f = (k < 576) ? ((k & 63) * 9 + (k >> 6)) : k;
            v = (n < 128) ? ptw1[f * 128 + n] : cfw1[f * 64 + (n - 128)];
        }
        int kk = k >> 5, hi = (k & 31) >> 3, j = k & 7, nt = n >> 4;
        int e = (((kk * 12 + nt) << 6) | (hi << 4) | (n & 15)) << 3 | j;
        w1hd[e] = f2h(v);
    }
    for (int s = gid; s < 8192; s += gs) {
        int k = s >> 6, n = s & 63;
        float v = ptw2[k * 64 + n];
        int kk = k >> 5, hi = (k & 31) >> 3, j = k & 7, nt = n >> 4;
        int e = ((((kk << 2) | nt) << 6) | (hi << 4) | (n & 15)) << 3 | j;
        w2hd[e] = f2h(v);
    }
    for (int e = gid; e < 2048; e += gs) {
        int j = e & 7, lane = (e >> 3) & 63, kk = e >> 9;
        int k = kk * 32 + ((lane >> 4) * 8) + j, n = lane & 15;
        float v = 0.f;
        if (k < 64) { if (n < 2) v = ptw3[k * 2 + n]; }
        else        { if (n == 2) v = cfw2[k - 64]; }
        w3hd[e] = f2h(v);
    }
}

// ---------------------------------------------------------------------------
// k_fused, round 13: identical structure to round 12 (8 waves / 32 samples,
// conv2 on 32x32x16) but __launch_bounds__(512, 4):
//   round 12's (512,6) capped regs at ~85 -> massive scratch spills
//   (FETCH 15->206 MB, WRITE 0.8->290 MB, 207 us). (512,4) gives a 128-reg
//   budget (no spill), 2 blocks/CU = 16 waves/CU = 4 waves/SIMD (vs 3 in r11).
// ---------------------------------------------------------------------------
#define BDS4 260
#define BDH4 (16 * BDS4)
#define A1S 584
#define A2S 296
#define FTS 616
#define HSH 200
#define RA_OFF 19712
#define O_OFF 26112
#define LDSTOT 26368

__device__ __forceinline__ f32x16 conv2_pool(const unsigned short* __restrict__ Ab,
                                             const h8 (&W2r)[9], int kh, float b2v,
                                             int pr, int pc) {
    f32x16 pool;
    #pragma unroll
    for (int r = 0; r < 16; r++) pool[r] = 0.f;
    #pragma unroll
    for (int sy = 0; sy < 2; sy++)
        #pragma unroll
        for (int sx = 0; sx < 2; sx++) {
            const int oy = pr * 2 + sy, ox = pc * 2 + sx;
            f32x16 acc;
            #pragma unroll
            for (int r = 0; r < 16; r++) acc[r] = 0.f;
            #pragma unroll
            for (int dy = -1; dy <= 1; dy++) {
                const int ry = oy + dy;
                if (ry < 0 || ry > 5) continue;
                #pragma unroll
                for (int dx = -1; dx <= 1; dx++) {
                    const int rx = ox + dx;
                    if (rx < 0 || rx > 5) continue;
                    h8 a = *(const h8*)&Ab[(ry * 6 + rx) * 16 + kh * 8];
                    acc = MFMA32(a, W2r[(dy + 1) * 3 + (dx + 1)], acc);
                }
            }
            #pragma unroll
            for (int r = 0; r < 16; r++)
                pool[r] = fmaxf(pool[r], acc[r] + b2v);  // relu fused via 0-init
        }
    return pool;
}

__global__ __launch_bounds__(512, 4) void k_fused(
    const float* __restrict__ board,
    const float* __restrict__ b1, const float* __restrict__ b2,
    const float* __restrict__ b3, const float* __restrict__ qp,
    const unsigned short* __restrict__ w1f,
    const unsigned short* __restrict__ w2f,
    const unsigned short* __restrict__ w3f,
    const unsigned short* __restrict__ w1hd,
    const unsigned short* __restrict__ w2hd,
    const unsigned short* __restrict__ w3hd,
    const float* __restrict__ ptb1, const float* __restrict__ ptb2,
    const float* __restrict__ ptb3, const float* __restrict__ cfb1,
    const float* __restrict__ cfb2,
    float* __restrict__ out)
{
    __shared__ __align__(16) unsigned short LDSH[LDSTOT];
    const int tid = threadIdx.x, wid = tid >> 6, lane = tid & 63;
    const int col = lane & 15, q = lane >> 4;
    const long long gg0 = (long long)blockIdx.x * 32;
    const f32x4 ZERO4 = {0.f, 0.f, 0.f, 0.f};

    unsigned short* Hb = LDSH + RA_OFF;               // overlays BD (dead)
    float* O = (float*)(LDSH + O_OFF);

    // ---- 1. zero BD staging buffer ----
    for (int e = tid; e < BDH4 / 4; e += 512)
        ((unsigned long long*)(LDSH + RA_OFF))[e] = 0ULL;
    __syncthreads();

    // ---- 2. per-group: stage board (ch-pad-4) -> quantum + conv1 ----
    float qv[2];
    h8 w1r0 = ((const h8*)w1f)[lane];
    h8 w1r1 = ((const h8*)w1f)[64 + lane];
    float b1v = b1[col];
    #pragma unroll
    for (int gi = 0; gi < 2; gi++) {
        for (int e = tid; e < 16 * 108; e += 512) {
            int r2 = e % 108, ch = r2 / 36, p = r2 % 36;
            int ss = e / 108;
            float v = board[(gg0 + gi * 16) * 108 + e];
            LDSH[RA_OFF + ss * BDS4 + ((p / 6 + 1) * 8 + (p % 6) + 1) * 4 + ch] =
                f2h(v);
        }
        __syncthreads();
        if (tid < 128) {
            int ss = tid >> 3, qq = tid & 7;
            int base = RA_OFF + ss * BDS4;
            int p8a = ((qq / 6 + 1) * 8 + (qq % 6) + 1) * 4;
            int e2 = (qq + 1) & 7;
            int p8b = ((e2 / 6 + 1) * 8 + (e2 % 6) + 1) * 4;
            float xq = h2f(LDSH[base + p8a]);
            float xn = h2f(LDSH[base + p8b]);
            float st = 0.f;
            for (int l = 0; l < 3; l++) {
                float a0 = qp[l * 24 + qq * 3], a1 = qp[l * 24 + qq * 3 + 1],
                      a2 = qp[l * 24 + qq * 3 + 2];
                st = sinf(a0 * xq) * cosf(a1 * xn) + tanhf(a2 * st);
            }
            qv[gi] = st;
        }
        {
            unsigned short* A1g = LDSH + gi * 9856;
            const int bs = RA_OFF + col * BDS4;
            const int rsel = q >> 1, wo = (q & 1) * 8;
            // 36 positions over 8 waves: waves 0-3 take 5, waves 4-7 take 4
            const int p0 = wid * 4 + (wid < 4 ? wid : 4);
            const int pe = p0 + (wid < 4 ? 5 : 4);
            for (int p = p0; p < pe; p++) {
                int y = p / 6, x = p % 6;
                int ab1 = bs + ((y + rsel) * 8 + x) * 4 + wo;
                int ab2 = bs + ((y + 2) * 8 + x) * 4 + wo;
                union { h8 v; h4 h[2]; } a1v, a2v;
                a1v.h[0] = *(const h4*)&LDSH[ab1];
                a1v.h[1] = *(const h4*)&LDSH[ab1 + 4];
                a2v.h[0] = *(const h4*)&LDSH[ab2];
                a2v.h[1] = *(const h4*)&LDSH[ab2 + 4];
                f32x4 c = MFMA16(a1v.v, w1r0, ZERO4);
                c = MFMA16(a2v.v, w1r1, c);
                #pragma unroll
                for (int r = 0; r < 4; r++)
                    A1g[(q * 4 + r) * A1S + p * 16 + col] =
                        f2h(fmaxf(c[r] + b1v, 0.f));
            }
        }
        __syncthreads();
    }

    // ---- 3. conv2 (32x32x16): wave wid owns pooled pos wid; wave 0 also pos 8
    {
        h8 W2r[9];
        #pragma unroll
        for (int t = 0; t < 9; t++)
            W2r[t] = ((const h8*)w2f)[t * 64 + lane];
        const int m32 = lane & 31, kh = lane >> 5;
        const float b2v = b2[m32];                  // oc = lane&31 in D
        const unsigned short* Ab = LDSH + (m32 >> 4) * 9856 + (m32 & 15) * A1S;

        if (wid == 0) {
            // 9th pooled pos: stash in scratch (BD region, dead) pre-barrier
            f32x16 p8 = conv2_pool(Ab, W2r, kh, b2v, 2, 2);
            #pragma unroll
            for (int r = 0; r < 16; r++) {
                int s = (r & 3) + 8 * (r >> 2) + 4 * kh;
                LDSH[RA_OFF + s * 32 + m32] = f2h(p8[r]);
            }
        }
        f32x16 pool = conv2_pool(Ab, W2r, kh, b2v, wid / 3, wid % 3);
        __syncthreads();   // all A1 reads (+ scratch write) done before A2 overlays
        #pragma unroll
        for (int r = 0; r < 16; r++) {
            int s = (r & 3) + 8 * (r >> 2) + 4 * kh;
            LDSH[(s >> 4) * 9856 + (s & 15) * A2S + wid * 32 + m32] = f2h(pool[r]);
        }
        for (int e = tid; e < 1024; e += 512) {     // copy scratch -> A2 pos 8
            int s = e >> 5;
            LDSH[(s >> 4) * 9856 + (s & 15) * A2S + 8 * 32 + (e & 31)] =
                LDSH[RA_OFF + e];
        }
    }
    __syncthreads();

    // ---- 4. conv3 -> registers: wave = (group, 16-oc tile) ----
    f32x4 c3[9];
    {
        const int g3 = wid >> 2, ot = wid & 3;
        const unsigned short* A2g = LDSH + g3 * 9856;
        h8 W3r[9];
        #pragma unroll
        for (int t = 0; t < 9; t++)
            W3r[t] = ((const h8*)w3f)[((ot >> 1) * 18 + t * 2 + (ot & 1)) * 64 + lane];
        const int sA2 = col * A2S;
        #pragma unroll
        for (int p = 0; p < 9; p++) {
            const int y = p / 3, x = p % 3;
            f32x4 acc = ZERO4;
            #pragma unroll
            for (int t = 0; t < 9; t++) {
                const int sy = y + t / 3 - 1, sx = x + t % 3 - 1;
                if (sy < 0 || sy >= 3 || sx < 0 || sx >= 3) continue;
                h8 a = *(const h8*)&A2g[sA2 + (sy * 3 + sx) * 32 + q * 8];
                acc = MFMA16(a, W3r[t], acc);
            }
            c3[p] = acc;
        }
    }
    __syncthreads();   // all A2 reads done before FT overlays region

    // ---- 5. write FT [p][oc] + quantum + zero tail cols 584..615 ----
    {
        const int g3 = wid >> 2, ot = wid & 3;
        float b3v = b3[ot * 16 + col];
        #pragma unroll
        for (int p = 0; p < 9; p++)
            #pragma unroll
            for (int r = 0; r < 4; r++) {
                int row = g3 * 16 + q * 4 + r;
                LDSH[row * FTS + p * 64 + ot * 16 + col] =
                    f2h(fmaxf(c3[p][r] + b3v, 0.f));
            }
        if (tid < 128) {
            int ss = tid >> 3, qq = tid & 7;
            LDSH[ss * FTS + 576 + qq] = f2h(qv[0]);
            LDSH[(ss + 16) * FTS + 576 + qq] = f2h(qv[1]);
        }
        for (int e = tid; e < 1024; e += 512)
            LDSH[(e >> 5) * FTS + 584 + (e & 31)] = 0;
    }
    __syncthreads();

    // ---- 6. heads L1: K=608 (19 kk); wave = (mt, 3 nt-tiles) of 24 tiles ----
    {
        f32x4 acc[3];
        acc[0] = ZERO4; acc[1] = ZERO4; acc[2] = ZERO4;
        const h8* wp1 = (const h8*)w1hd;
        const int mt = wid & 1, ntb = (wid >> 1) * 3;
        for (int kk = 0; kk < 19; kk++) {
            h8 a = *(const h8*)&LDSH[(mt * 16 + col) * FTS + kk * 32 + q * 8];
            #pragma unroll
            for (int nt = 0; nt < 3; nt++) {
                h8 b = wp1[(kk * 12 + ntb + nt) * 64 + lane];
                acc[nt] = MFMA16(a, b, acc[nt]);
            }
        }
        #pragma unroll
        for (int nt = 0; nt < 3; nt++) {
            int ntg = ntb + nt;
            float bv = (ntg < 8) ? ptb1[ntg * 16 + col] : cfb1[(ntg - 8) * 16 + col];
            #pragma unroll
            for (int r = 0; r < 4; r++)
                Hb[(mt * 16 + q * 4 + r) * HSH + ntg * 16 + col] =
                    f2h(fmaxf(acc[nt][r] + bv, 0.f));
        }
    }
    __syncthreads();

    // ---- 7. heads L2: wave = (mt, nt) of 8 tiles ----
    {
        f32x4 acc2 = ZERO4;
        const h8* wp2 = (const h8*)w2hd;
        const int mt = wid & 1, nt2 = wid >> 1;
        #pragma unroll
        for (int kk = 0; kk < 4; kk++) {
            h8 a = *(const h8*)&Hb[(mt * 16 + col) * HSH + kk * 32 + q * 8];
            h8 b = wp2[(kk * 4 + nt2) * 64 + lane];
            acc2 = MFMA16(a, b, acc2);
        }
        __syncthreads();   // all L2 reads done before overwriting cols 0..63
        float bv2 = ptb2[nt2 * 16 + col];
        #pragma unroll
        for (int r = 0; r < 4; r++)
            Hb[(mt * 16 + q * 4 + r) * HSH + nt2 * 16 + col] =
                f2h(fmaxf(acc2[r] + bv2, 0.f));
    }
    __syncthreads();

    // ---- 8. heads L3 + epilogue: waves 0,1 handle mt = wid ----
    if (wid < 2) {
        const int mt = wid;
        f32x4 a3 = ZERO4;
        #pragma unroll
        for (int kk = 0; kk < 4; kk++) {
            int base = (kk < 2) ? kk * 32 : kk * 32 + 64;
            h8 a = *(const h8*)&Hb[(mt * 16 + col) * HSH + base + q * 8];
            h8 b = ((const h8*)w3hd)[kk * 64 + lane];
            a3 = MFMA16(a, b, a3);
        }
        if (col < 3) {
            float bv = (col < 2) ? ptb3[col] : cfb2[0];
            #pragma unroll
            for (int r = 0; r < 4; r++)
                O[(mt * 16 + q * 4 + r) * 4 + col] = a3[r] + bv;
        }
        if (lane < 16) {
            int s = mt * 16 + lane;
            float l0 = O[s * 4 + 0], l1 = O[s * 4 + 1], l2 = O[s * 4 + 2];
            float m = fmaxf(l0, l1);
            float e0 = expf(l0 - m), e1 = expf(l1 - m);
            float inv = 1.f / (e0 + e1);
            float* op = out + (gg0 + s) * 3;
            op[0] = e0 * inv;
            op[1] = e1 * inv;
            op[2] = 1.f / (1.f + expf(-l2));
        }
    }
}

extern "C" void kernel_launch(void* const* d_in, const int* in_sizes, int n_in,
                              void* d_out, int out_size, void* d_ws, size_t ws_size,
                              hipStream_t stream) {
    const float* board = (const float*)d_in[0];
    const float* c1w  = (const float*)d_in[2];
    const float* c1b  = (const float*)d_in[3];
    const float* c2w  = (const float*)d_in[4];
    const float* c2b  = (const float*)d_in[5];
    const float* c3w  = (const float*)d_in[6];
    const float* c3b  = (const float*)d_in[7];
    const float* qp   = (const float*)d_in[8];
    const float* ptw1 = (const float*)d_in[9];
    const float* ptb1 = (const float*)d_in[10];
    const float* ptw2 = (const float*)d_in[11];
    const float* ptb2 = (const float*)d_in[12];
    const float* ptw3 = (const float*)d_in[13];
    const float* ptb3 = (const float*)d_in[14];
    const float* cfw1 = (const float*)d_in[15];
    const float* cfb1 = (const float*)d_in[16];
    const float* cfw2 = (const float*)d_in[17];
    const float* cfb2 = (const float*)d_in[18];
    float* out = (float*)d_out;

    int Btot = in_sizes[0] / 108;          // 65536

    unsigned short* w1f   = (unsigned short*)d_ws;
    unsigned short* w2f   = (unsigned short*)((char*)d_ws + 2048);
    unsigned short* w3f   = (unsigned short*)((char*)d_ws + 20480);
    unsigned short* w1hd  = (unsigned short*)((char*)d_ws + 57344);
    unsigned short* w2hd  = (unsigned short*)((char*)d_ws + 290816);
    unsigned short* w3hd  = (unsigned short*)((char*)d_ws + 307200);

    hipLaunchKernelGGL(k_prep, dim3(256), dim3(256), 0, stream,
                       c1w, c2w, c3w, ptw1, cfw1, ptw2, ptw3, cfw2,
                       w1f, w2f, w3f, w1hd, w2hd, w3hd);
    hipLaunchKernelGGL(k_fused, dim3(Btot / 32), dim3(512), 0, stream,
                       board, c1b, c2b, c3b, qp, w1f, w2f, w3f,
                       w1hd, w2hd, w3hd, ptb1, ptb2, ptb3, cfb1, cfb2, out);
}